// Round 1
// baseline (3009.474 us; speedup 1.0000x reference)
//
#include <hip/hip_runtime.h>
#include <math.h>

#define BB 2
#define VV 8
#define NQ 336
#define DD 256
#define HEADS 8
#define HD 32
#define FF 1024
#define NL 6
#define BQ (BB*NQ)
#define W_IMG 512
#define H_IMG 512

// ---------------- feature transpose: (BV, D, H, W) -> (BV, H, W, D) ----------------
__global__ __launch_bounds__(256) void transpose_feat(const float* __restrict__ src,
                                                      float* __restrict__ dst,
                                                      int H, int Wd) {
    long idx = (long)blockIdx.x * blockDim.x + threadIdx.x;
    int d = idx & (DD - 1);
    long rest = idx >> 8;          // / DD
    int x = rest % Wd; rest /= Wd;
    int y = rest % H;  rest /= H;
    int bv = (int)rest;
    dst[idx] = src[((long)(bv * DD + d) * H + y) * Wd + x];
}

// ---------------- QKV projection: q,k from (x+qp), v from x ----------------
__global__ __launch_bounds__(256) void qkv_kernel(const float* __restrict__ x,
                                                  const float* __restrict__ qp,
                                                  const float* __restrict__ Wqkv,
                                                  const float* __restrict__ bqkv,
                                                  float* __restrict__ qkv) {
    __shared__ float sx[DD];
    __shared__ float sxq[DD];
    int row = blockIdx.x;
    int j = threadIdx.x;
    float xv = x[(size_t)row * DD + j];
    sx[j] = xv;
    sxq[j] = xv + qp[(size_t)row * DD + j];
    __syncthreads();
    float accq = bqkv[j], acck = bqkv[DD + j], accv = bqkv[2 * DD + j];
    const float* wq = Wqkv + (size_t)j * DD;
    const float* wk = Wqkv + (size_t)(DD + j) * DD;
    const float* wv = Wqkv + (size_t)(2 * DD + j) * DD;
    for (int k = 0; k < DD; k += 4) {
        float4 a  = *(const float4*)(sxq + k);
        float4 av = *(const float4*)(sx + k);
        float4 w1 = *(const float4*)(wq + k);
        float4 w2 = *(const float4*)(wk + k);
        float4 w3 = *(const float4*)(wv + k);
        accq = fmaf(a.x,  w1.x, accq); accq = fmaf(a.y,  w1.y, accq);
        accq = fmaf(a.z,  w1.z, accq); accq = fmaf(a.w,  w1.w, accq);
        acck = fmaf(a.x,  w2.x, acck); acck = fmaf(a.y,  w2.y, acck);
        acck = fmaf(a.z,  w2.z, acck); acck = fmaf(a.w,  w2.w, acck);
        accv = fmaf(av.x, w3.x, accv); accv = fmaf(av.y, w3.y, accv);
        accv = fmaf(av.z, w3.z, accv); accv = fmaf(av.w, w3.w, accv);
    }
    size_t base = (size_t)row * (3 * DD);
    qkv[base + j] = accq;
    qkv[base + DD + j] = acck;
    qkv[base + 2 * DD + j] = accv;
}

// ---------------- attention: one wave per (b,h,q) ----------------
__global__ __launch_bounds__(64) void attn_kernel(const float* __restrict__ qkv,
                                                  float* __restrict__ attn_o) {
    int blk = blockIdx.x;
    int q = blk % NQ;
    int bh = blk / NQ;
    int h = bh % HEADS;
    int b = bh / HEADS;
    int t = threadIdx.x;
    __shared__ float sq[HD];
    __shared__ float se[NQ];
    const float scale = 0.17677669529663687f; // 1/sqrt(32)
    const float* qrow = qkv + ((size_t)(b * NQ + q) * (3 * DD)) + h * HD;
    if (t < HD) sq[t] = qrow[t];
    __syncthreads();
    float lmax = -1e30f;
    for (int kk = t; kk < NQ; kk += 64) {
        const float* krow = qkv + ((size_t)(b * NQ + kk) * (3 * DD)) + DD + h * HD;
        float s = 0.f;
        for (int d = 0; d < HD; d += 4) {
            float4 kv = *(const float4*)(krow + d);
            s = fmaf(sq[d],     kv.x, s);
            s = fmaf(sq[d + 1], kv.y, s);
            s = fmaf(sq[d + 2], kv.z, s);
            s = fmaf(sq[d + 3], kv.w, s);
        }
        se[kk] = s * scale;
        lmax = fmaxf(lmax, s * scale);
    }
    for (int o2 = 32; o2 > 0; o2 >>= 1) lmax = fmaxf(lmax, __shfl_down(lmax, o2));
    lmax = __shfl(lmax, 0);
    __syncthreads();
    float lsum = 0.f;
    for (int kk = t; kk < NQ; kk += 64) {
        float e = expf(se[kk] - lmax);
        se[kk] = e;
        lsum += e;
    }
    for (int o2 = 32; o2 > 0; o2 >>= 1) lsum += __shfl_down(lsum, o2);
    lsum = __shfl(lsum, 0);
    __syncthreads();
    float inv = 1.f / lsum;
    int d = t & 31;
    int half = t >> 5;
    float acc = 0.f;
    for (int kk = half; kk < NQ; kk += 2) {
        acc = fmaf(se[kk], qkv[((size_t)(b * NQ + kk) * (3 * DD)) + 2 * DD + h * HD + d], acc);
    }
    acc += __shfl_xor(acc, 32);
    if (half == 0) attn_o[((size_t)(b * NQ + q)) * DD + h * HD + d] = acc * inv;
}

// ---------------- fused GEMM(NxK,N=256) + residual + LayerNorm, in-place on x ----------------
template <int K>
__global__ __launch_bounds__(256) void gemm_res_ln(const float* __restrict__ A,
                                                   const float* __restrict__ Wt,
                                                   const float* __restrict__ bias,
                                                   const float* __restrict__ gam,
                                                   const float* __restrict__ bet,
                                                   float* __restrict__ x) {
    __shared__ float sA[K];
    __shared__ float wsum[4], wsum2[4];
    __shared__ float stats[2];
    int row = blockIdx.x;
    int j = threadIdx.x;
    for (int k = j; k < K; k += 256) sA[k] = A[(size_t)row * K + k];
    __syncthreads();
    float acc = bias[j];
    const float* wp = Wt + (size_t)j * K;
    for (int k = 0; k < K; k += 4) {
        float4 a  = *(const float4*)(sA + k);
        float4 wv = *(const float4*)(wp + k);
        acc = fmaf(a.x, wv.x, acc); acc = fmaf(a.y, wv.y, acc);
        acc = fmaf(a.z, wv.z, acc); acc = fmaf(a.w, wv.w, acc);
    }
    float val = x[(size_t)row * DD + j] + acc;
    float s = val, s2 = val * val;
    for (int o2 = 32; o2 > 0; o2 >>= 1) {
        s  += __shfl_down(s, o2);
        s2 += __shfl_down(s2, o2);
    }
    int wid = j >> 6, lane = j & 63;
    if (lane == 0) { wsum[wid] = s; wsum2[wid] = s2; }
    __syncthreads();
    if (j == 0) {
        float ts  = wsum[0] + wsum[1] + wsum[2] + wsum[3];
        float ts2 = wsum2[0] + wsum2[1] + wsum2[2] + wsum2[3];
        float mean = ts * (1.f / DD);
        float var = ts2 * (1.f / DD) - mean * mean;
        stats[0] = mean;
        stats[1] = rsqrtf(var + 1e-5f);
    }
    __syncthreads();
    x[(size_t)row * DD + j] = (val - stats[0]) * stats[1] * gam[j] + bet[j];
}

// ---------------- GEMM + bias + ReLU (N = NP*256) ----------------
template <int K, int NP>
__global__ __launch_bounds__(256) void gemm_relu(const float* __restrict__ A,
                                                 const float* __restrict__ Wt,
                                                 const float* __restrict__ bias,
                                                 float* __restrict__ out, int N) {
    __shared__ float sA[K];
    int row = blockIdx.x;
    int tid = threadIdx.x;
    for (int k = tid; k < K; k += 256) sA[k] = A[(size_t)row * K + k];
    __syncthreads();
    for (int p = 0; p < NP; ++p) {
        int j = tid + p * 256;
        float acc = bias[j];
        const float* wp = Wt + (size_t)j * K;
        for (int k = 0; k < K; k += 4) {
            float4 a  = *(const float4*)(sA + k);
            float4 wv = *(const float4*)(wp + k);
            acc = fmaf(a.x, wv.x, acc); acc = fmaf(a.y, wv.y, acc);
            acc = fmaf(a.z, wv.z, acc); acc = fmaf(a.w, wv.w, acc);
        }
        out[(size_t)row * N + j] = fmaxf(acc, 0.f);
    }
}

// ---------------- camera projection of reference points ----------------
__global__ __launch_bounds__(256) void project_kernel(const float* __restrict__ ref,
                                                      const float* __restrict__ Rm,
                                                      const float* __restrict__ Tm,
                                                      const float* __restrict__ Km,
                                                      float* __restrict__ grid) {
    int idx = blockIdx.x * blockDim.x + threadIdx.x;
    if (idx >= BB * VV * NQ) return;
    int q = idx % NQ;
    int bv = idx / NQ;
    int b = bv / VV;
    const float* r = ref + ((size_t)b * NQ + q) * 3;
    const float* R = Rm + (size_t)bv * 9;
    const float* T = Tm + (size_t)bv * 3;
    const float* K = Km + (size_t)bv * 9;
    float p0 = R[0] * r[0] + R[1] * r[1] + R[2] * r[2] + T[0];
    float p1 = R[3] * r[0] + R[4] * r[1] + R[5] * r[2] + T[1];
    float p2 = R[6] * r[0] + R[7] * r[1] + R[8] * r[2] + T[2];
    float z = fmaxf(p2, 0.1f);
    float u  = p0 * K[0] / z + K[2];
    float vv = p1 * K[4] / z + K[5];
    float un = 2.f * u  / (float)(W_IMG - 1) - 1.f;
    float vn = 2.f * vv / (float)(H_IMG - 1) - 1.f;
    bool m = (un > -1.f) && (un < 1.f) && (vn > -1.f) && (vn < 1.f) && (p2 > 0.f);
    grid[(size_t)idx * 3 + 0] = un;
    grid[(size_t)idx * 3 + 1] = vn;
    grid[(size_t)idx * 3 + 2] = m ? 1.f : 0.f;
}

// ---------------- bilinear sample one level, one channel ----------------
template <bool TRANSPOSED>
__device__ inline float sample_level(const float* __restrict__ f, int bv, int Hh,
                                     float un, float vn, int dth) {
    int Ww = Hh;
    float xx = (un + 1.f) * Ww * 0.5f - 0.5f;
    float yy = (vn + 1.f) * Hh * 0.5f - 0.5f;
    float x0f = floorf(xx), y0f = floorf(yy);
    int ix0 = (int)x0f, iy0 = (int)y0f;
    float wx1 = xx - x0f, wx0 = 1.f - wx1;
    float wy1 = yy - y0f, wy0 = 1.f - wy1;
    float s = 0.f;
#define TAP(IX, IY, W)                                                           \
    {                                                                            \
        int ix = (IX), iy = (IY);                                                \
        if (ix >= 0 && ix < Ww && iy >= 0 && iy < Hh) {                          \
            float v;                                                             \
            if (TRANSPOSED)                                                      \
                v = f[((size_t)bv * Hh * Ww + (size_t)iy * Ww + ix) * DD + dth]; \
            else                                                                 \
                v = f[(((size_t)bv * DD + dth) * Hh + iy) * Ww + ix];            \
            s = fmaf((W), v, s);                                                 \
        }                                                                        \
    }
    TAP(ix0,     iy0,     wy0 * wx0)
    TAP(ix0 + 1, iy0,     wy0 * wx1)
    TAP(ix0,     iy0 + 1, wy1 * wx0)
    TAP(ix0 + 1, iy0 + 1, wy1 * wx1)
#undef TAP
    return s;
}

// ---------------- multi-view multi-level sample + mask fuse ----------------
template <bool TRANSPOSED>
__global__ __launch_bounds__(256) void sample_fuse(const float* __restrict__ f0,
                                                   const float* __restrict__ f1,
                                                   const float* __restrict__ f2,
                                                   const float* __restrict__ grid,
                                                   float* __restrict__ fused) {
    int row = blockIdx.x;            // b*NQ + q
    int dth = threadIdx.x;
    int b = row / NQ;
    int q = row % NQ;
    float acc = 0.f;
    float cnt = 0.f;
    for (int v = 0; v < VV; ++v) {
        int bv = b * VV + v;
        size_t gidx = ((size_t)bv * NQ + q) * 3;
        float un = grid[gidx], vn = grid[gidx + 1], m = grid[gidx + 2];
        if (m == 0.f) continue;
        cnt += 1.f;
        float ms = sample_level<TRANSPOSED>(f0, bv, 64, un, vn, dth)
                 + sample_level<TRANSPOSED>(f1, bv, 32, un, vn, dth)
                 + sample_level<TRANSPOSED>(f2, bv, 16, un, vn, dth);
        acc += ms * (1.f / 3.f);
    }
    fused[(size_t)row * DD + dth] = acc / fmaxf(cnt, 1.f);
}

// ---------------- pose delta (3 dots) + classification (1 dot), ref update ----------------
__global__ __launch_bounds__(256) void pose_cls(const float* __restrict__ h2,
                                                const float* __restrict__ x,
                                                const float* __restrict__ pw2,
                                                const float* __restrict__ pb2,
                                                const float* __restrict__ cW,
                                                const float* __restrict__ cb,
                                                float* __restrict__ refb,
                                                float* __restrict__ outp) {
    int row = blockIdx.x;
    int tid = threadIdx.x;
    __shared__ float rbuf[4][4];
    float hv = h2[(size_t)row * DD + tid];
    float xv = x[(size_t)row * DD + tid];
    float v0 = hv * pw2[tid];
    float v1 = hv * pw2[DD + tid];
    float v2 = hv * pw2[2 * DD + tid];
    float v3 = xv * cW[tid];
    for (int o2 = 32; o2 > 0; o2 >>= 1) {
        v0 += __shfl_down(v0, o2);
        v1 += __shfl_down(v1, o2);
        v2 += __shfl_down(v2, o2);
        v3 += __shfl_down(v3, o2);
    }
    int wid = tid >> 6, lane = tid & 63;
    if (lane == 0) { rbuf[0][wid] = v0; rbuf[1][wid] = v1; rbuf[2][wid] = v2; rbuf[3][wid] = v3; }
    __syncthreads();
    if (tid == 0) {
        float d0 = rbuf[0][0] + rbuf[0][1] + rbuf[0][2] + rbuf[0][3] + pb2[0];
        float d1 = rbuf[1][0] + rbuf[1][1] + rbuf[1][2] + rbuf[1][3] + pb2[1];
        float d2 = rbuf[2][0] + rbuf[2][1] + rbuf[2][2] + rbuf[2][3] + pb2[2];
        float cl = rbuf[3][0] + rbuf[3][1] + rbuf[3][2] + rbuf[3][3] + cb[0];
        float r0 = refb[(size_t)row * 3 + 0] + d0;
        float r1 = refb[(size_t)row * 3 + 1] + d1;
        float r2 = refb[(size_t)row * 3 + 2] + d2;
        refb[(size_t)row * 3 + 0] = r0;
        refb[(size_t)row * 3 + 1] = r1;
        refb[(size_t)row * 3 + 2] = r2;
        outp[(size_t)row * 4 + 0] = cl;
        outp[(size_t)row * 4 + 1] = r0;
        outp[(size_t)row * 4 + 2] = r1;
        outp[(size_t)row * 4 + 3] = r2;
    }
}

extern "C" void kernel_launch(void* const* d_in, const int* in_sizes, int n_in,
                              void* d_out, int out_size, void* d_ws, size_t ws_size,
                              hipStream_t stream) {
    const float* tgt       = (const float*)d_in[0];
    const float* query_pos = (const float*)d_in[1];
    const float* refpts    = (const float*)d_in[2];
    const float* feat0     = (const float*)d_in[3];
    const float* feat1     = (const float*)d_in[4];
    const float* feat2     = (const float*)d_in[5];
    const float* camR      = (const float*)d_in[6];
    const float* camT      = (const float*)d_in[7];
    const float* camK      = (const float*)d_in[8];
    const float* Wqkv      = (const float*)d_in[9];
    const float* bqkv      = (const float*)d_in[10];
    const float* Wo        = (const float*)d_in[11];
    const float* bo        = (const float*)d_in[12];
    const float* ln1_g     = (const float*)d_in[13];
    const float* ln1_b     = (const float*)d_in[14];
    const float* Wproj     = (const float*)d_in[15];
    const float* bproj     = (const float*)d_in[16];
    const float* pn_g      = (const float*)d_in[17];
    const float* pn_b      = (const float*)d_in[18];
    const float* W1        = (const float*)d_in[19];
    const float* b1        = (const float*)d_in[20];
    const float* W2        = (const float*)d_in[21];
    const float* b2        = (const float*)d_in[22];
    const float* ln2_g     = (const float*)d_in[23];
    const float* ln2_b     = (const float*)d_in[24];
    const float* pose_W0   = (const float*)d_in[25];
    const float* pose_b0   = (const float*)d_in[26];
    const float* pose_W1   = (const float*)d_in[27];
    const float* pose_b1   = (const float*)d_in[28];
    const float* pose_W2   = (const float*)d_in[29];
    const float* pose_b2   = (const float*)d_in[30];
    const float* cls_W     = (const float*)d_in[31];
    const float* cls_b     = (const float*)d_in[32];
    float* out = (float*)d_out;

    float* w = (float*)d_ws;
    size_t off = 0;
    auto alloc = [&](size_t n) { float* p = w + off; off += n; return p; };
    float* x      = alloc((size_t)BQ * DD);
    float* qkv    = alloc((size_t)BQ * 3 * DD);
    float* attn_o = alloc((size_t)BQ * DD);
    float* grid   = alloc((size_t)BB * VV * NQ * 3);
    float* fused  = alloc((size_t)BQ * DD);
    float* ffh    = alloc((size_t)BQ * FF);
    float* h1b    = alloc((size_t)BQ * DD);
    float* h2b    = alloc((size_t)BQ * DD);
    float* refb   = alloc((size_t)BQ * 3);
    size_t base_floats = off;
    size_t featT_floats = (size_t)BB * VV * DD * (64 * 64 + 32 * 32 + 16 * 16);
    bool useT = ws_size >= (base_floats + featT_floats) * sizeof(float);
    float *fT0 = nullptr, *fT1 = nullptr, *fT2 = nullptr;
    if (useT) {
        fT0 = alloc((size_t)BB * VV * 64 * 64 * DD);
        fT1 = alloc((size_t)BB * VV * 32 * 32 * DD);
        fT2 = alloc((size_t)BB * VV * 16 * 16 * DD);
    }

    hipMemcpyAsync(x, tgt, (size_t)BQ * DD * sizeof(float), hipMemcpyDeviceToDevice, stream);
    hipMemcpyAsync(refb, refpts, (size_t)BQ * 3 * sizeof(float), hipMemcpyDeviceToDevice, stream);

    if (useT) {
        transpose_feat<<<(BB * VV * 64 * 64 * DD) / 256, 256, 0, stream>>>(feat0, fT0, 64, 64);
        transpose_feat<<<(BB * VV * 32 * 32 * DD) / 256, 256, 0, stream>>>(feat1, fT1, 32, 32);
        transpose_feat<<<(BB * VV * 16 * 16 * DD) / 256, 256, 0, stream>>>(feat2, fT2, 16, 16);
    }

    for (int l = 0; l < NL; ++l) {
        qkv_kernel<<<BQ, 256, 0, stream>>>(x, query_pos,
                                           Wqkv + (size_t)l * 3 * DD * DD,
                                           bqkv + (size_t)l * 3 * DD, qkv);
        attn_kernel<<<BB * HEADS * NQ, 64, 0, stream>>>(qkv, attn_o);
        gemm_res_ln<DD><<<BQ, 256, 0, stream>>>(attn_o,
                                                Wo + (size_t)l * DD * DD, bo + (size_t)l * DD,
                                                ln1_g + (size_t)l * DD, ln1_b + (size_t)l * DD, x);
        project_kernel<<<(BB * VV * NQ + 255) / 256, 256, 0, stream>>>(refb, camR, camT, camK, grid);
        if (useT)
            sample_fuse<true><<<BQ, 256, 0, stream>>>(fT0, fT1, fT2, grid, fused);
        else
            sample_fuse<false><<<BQ, 256, 0, stream>>>(feat0, feat1, feat2, grid, fused);
        gemm_res_ln<DD><<<BQ, 256, 0, stream>>>(fused,
                                                Wproj + (size_t)l * DD * DD, bproj + (size_t)l * DD,
                                                pn_g + (size_t)l * DD, pn_b + (size_t)l * DD, x);
        gemm_relu<DD, 4><<<BQ, 256, 0, stream>>>(x, W1 + (size_t)l * FF * DD,
                                                 b1 + (size_t)l * FF, ffh, FF);
        gemm_res_ln<FF><<<BQ, 256, 0, stream>>>(ffh,
                                                W2 + (size_t)l * DD * FF, b2 + (size_t)l * DD,
                                                ln2_g + (size_t)l * DD, ln2_b + (size_t)l * DD, x);
        gemm_relu<DD, 1><<<BQ, 256, 0, stream>>>(x, pose_W0, pose_b0, h1b, DD);
        gemm_relu<DD, 1><<<BQ, 256, 0, stream>>>(h1b, pose_W1, pose_b1, h2b, DD);
        pose_cls<<<BQ, 256, 0, stream>>>(h2b, x, pose_W2, pose_b2, cls_W, cls_b,
                                         refb, out + (size_t)l * BQ * 4);
    }
}

// Round 2
// 1944.285 us; speedup vs baseline: 1.5479x; 1.5479x over previous
//
#include <hip/hip_runtime.h>
#include <math.h>

#define BB 2
#define VV 8
#define NQ 336
#define DD 256
#define HEADS 8
#define HD 32
#define FF 1024
#define NL 6
#define BQ (BB*NQ)
#define W_IMG 512
#define H_IMG 512

// ---------------- merged LDS-tiled transpose: (BV,D,H,W) -> (BV,H,W,D) for all 3 levels ----
// blocks: level0 16bv*64pt*4cg=4096, level1 16*16*4=1024, level2 16*4*4=256 => 5376
__global__ __launch_bounds__(256) void transpose_all(const float* __restrict__ f0,
                                                     const float* __restrict__ f1,
                                                     const float* __restrict__ f2,
                                                     float* __restrict__ o0,
                                                     float* __restrict__ o1,
                                                     float* __restrict__ o2) {
    int b = blockIdx.x;
    const float* src; float* dst; int HW, ptiles;
    if (b < 4096)      { src = f0; dst = o0; HW = 4096; ptiles = 64; }
    else if (b < 5120) { b -= 4096; src = f1; dst = o1; HW = 1024; ptiles = 16; }
    else               { b -= 5120; src = f2; dst = o2; HW = 256;  ptiles = 4;  }
    int cg = b & 3;
    int pt = (b >> 2) % ptiles;
    int bv = (b >> 2) / ptiles;
    int d0 = cg * 64, p0 = pt * 64;
    __shared__ float tile[64][65];
    int tid = threadIdx.x;
    int t4 = tid >> 4, t15 = tid & 15;
    #pragma unroll
    for (int pass = 0; pass < 4; ++pass) {
        int d = pass * 16 + t4;
        int p = t15 * 4;
        float4 v = *(const float4*)(src + ((size_t)(bv * DD + d0 + d)) * HW + p0 + p);
        tile[d][p] = v.x; tile[d][p + 1] = v.y; tile[d][p + 2] = v.z; tile[d][p + 3] = v.w;
    }
    __syncthreads();
    #pragma unroll
    for (int pass = 0; pass < 4; ++pass) {
        int p = pass * 16 + t4;
        int d = t15 * 4;
        float4 v = make_float4(tile[d][p], tile[d + 1][p], tile[d + 2][p], tile[d + 3][p]);
        *(float4*)(dst + ((size_t)bv * HW + p0 + p) * DD + d0 + d) = v;
    }
}

// ---------------- QKV projection, 4 rows per block ----------------
__global__ __launch_bounds__(256) void qkv4_kernel(const float* __restrict__ x,
                                                   const float* __restrict__ qp,
                                                   const float* __restrict__ Wqkv,
                                                   const float* __restrict__ bqkv,
                                                   float* __restrict__ qkv) {
    __shared__ float sX[4 * DD];
    __shared__ float sQ[4 * DD];
    int r0 = blockIdx.x * 4;
    int j = threadIdx.x;
    {
        const float4* xs = (const float4*)(x + (size_t)r0 * DD);
        const float4* qs = (const float4*)(qp + (size_t)r0 * DD);
        float4 xv = xs[j];
        float4 qv = qs[j];
        ((float4*)sX)[j] = xv;
        ((float4*)sQ)[j] = make_float4(xv.x + qv.x, xv.y + qv.y, xv.z + qv.z, xv.w + qv.w);
    }
    __syncthreads();
    float aq0 = bqkv[j], aq1 = aq0, aq2 = aq0, aq3 = aq0;
    float ak0 = bqkv[DD + j], ak1 = ak0, ak2 = ak0, ak3 = ak0;
    float av0 = bqkv[2 * DD + j], av1 = av0, av2 = av0, av3 = av0;
    const float* wq = Wqkv + (size_t)j * DD;
    const float* wk = Wqkv + (size_t)(DD + j) * DD;
    const float* wv = Wqkv + (size_t)(2 * DD + j) * DD;
    for (int k = 0; k < DD; k += 4) {
        float4 w1 = *(const float4*)(wq + k);
        float4 w2 = *(const float4*)(wk + k);
        float4 w3 = *(const float4*)(wv + k);
        float4 q0 = *(const float4*)(sQ + 0 * DD + k);
        float4 q1 = *(const float4*)(sQ + 1 * DD + k);
        float4 q2 = *(const float4*)(sQ + 2 * DD + k);
        float4 q3 = *(const float4*)(sQ + 3 * DD + k);
        float4 x0 = *(const float4*)(sX + 0 * DD + k);
        float4 x1 = *(const float4*)(sX + 1 * DD + k);
        float4 x2 = *(const float4*)(sX + 2 * DD + k);
        float4 x3 = *(const float4*)(sX + 3 * DD + k);
        aq0 = fmaf(q0.x, w1.x, aq0); aq0 = fmaf(q0.y, w1.y, aq0); aq0 = fmaf(q0.z, w1.z, aq0); aq0 = fmaf(q0.w, w1.w, aq0);
        aq1 = fmaf(q1.x, w1.x, aq1); aq1 = fmaf(q1.y, w1.y, aq1); aq1 = fmaf(q1.z, w1.z, aq1); aq1 = fmaf(q1.w, w1.w, aq1);
        aq2 = fmaf(q2.x, w1.x, aq2); aq2 = fmaf(q2.y, w1.y, aq2); aq2 = fmaf(q2.z, w1.z, aq2); aq2 = fmaf(q2.w, w1.w, aq2);
        aq3 = fmaf(q3.x, w1.x, aq3); aq3 = fmaf(q3.y, w1.y, aq3); aq3 = fmaf(q3.z, w1.z, aq3); aq3 = fmaf(q3.w, w1.w, aq3);
        ak0 = fmaf(q0.x, w2.x, ak0); ak0 = fmaf(q0.y, w2.y, ak0); ak0 = fmaf(q0.z, w2.z, ak0); ak0 = fmaf(q0.w, w2.w, ak0);
        ak1 = fmaf(q1.x, w2.x, ak1); ak1 = fmaf(q1.y, w2.y, ak1); ak1 = fmaf(q1.z, w2.z, ak1); ak1 = fmaf(q1.w, w2.w, ak1);
        ak2 = fmaf(q2.x, w2.x, ak2); ak2 = fmaf(q2.y, w2.y, ak2); ak2 = fmaf(q2.z, w2.z, ak2); ak2 = fmaf(q2.w, w2.w, ak2);
        ak3 = fmaf(q3.x, w2.x, ak3); ak3 = fmaf(q3.y, w2.y, ak3); ak3 = fmaf(q3.z, w2.z, ak3); ak3 = fmaf(q3.w, w2.w, ak3);
        av0 = fmaf(x0.x, w3.x, av0); av0 = fmaf(x0.y, w3.y, av0); av0 = fmaf(x0.z, w3.z, av0); av0 = fmaf(x0.w, w3.w, av0);
        av1 = fmaf(x1.x, w3.x, av1); av1 = fmaf(x1.y, w3.y, av1); av1 = fmaf(x1.z, w3.z, av1); av1 = fmaf(x1.w, w3.w, av1);
        av2 = fmaf(x2.x, w3.x, av2); av2 = fmaf(x2.y, w3.y, av2); av2 = fmaf(x2.z, w3.z, av2); av2 = fmaf(x2.w, w3.w, av2);
        av3 = fmaf(x3.x, w3.x, av3); av3 = fmaf(x3.y, w3.y, av3); av3 = fmaf(x3.z, w3.z, av3); av3 = fmaf(x3.w, w3.w, av3);
    }
    size_t b0 = (size_t)(r0 + 0) * (3 * DD);
    size_t b1 = (size_t)(r0 + 1) * (3 * DD);
    size_t b2 = (size_t)(r0 + 2) * (3 * DD);
    size_t b3 = (size_t)(r0 + 3) * (3 * DD);
    qkv[b0 + j] = aq0; qkv[b0 + DD + j] = ak0; qkv[b0 + 2 * DD + j] = av0;
    qkv[b1 + j] = aq1; qkv[b1 + DD + j] = ak1; qkv[b1 + 2 * DD + j] = av1;
    qkv[b2 + j] = aq2; qkv[b2 + DD + j] = ak2; qkv[b2 + 2 * DD + j] = av2;
    qkv[b3 + j] = aq3; qkv[b3 + DD + j] = ak3; qkv[b3 + 2 * DD + j] = av3;
}

// ---------------- attention: one wave per (b,h,q) ----------------
__global__ __launch_bounds__(64) void attn_kernel(const float* __restrict__ qkv,
                                                  float* __restrict__ attn_o) {
    int blk = blockIdx.x;
    int q = blk % NQ;
    int bh = blk / NQ;
    int h = bh % HEADS;
    int b = bh / HEADS;
    int t = threadIdx.x;
    __shared__ float sq[HD];
    __shared__ float se[NQ];
    const float scale = 0.17677669529663687f; // 1/sqrt(32)
    const float* qrow = qkv + ((size_t)(b * NQ + q) * (3 * DD)) + h * HD;
    if (t < HD) sq[t] = qrow[t];
    __syncthreads();
    float lmax = -1e30f;
    for (int kk = t; kk < NQ; kk += 64) {
        const float* krow = qkv + ((size_t)(b * NQ + kk) * (3 * DD)) + DD + h * HD;
        float s = 0.f;
        for (int d = 0; d < HD; d += 4) {
            float4 kv = *(const float4*)(krow + d);
            s = fmaf(sq[d],     kv.x, s);
            s = fmaf(sq[d + 1], kv.y, s);
            s = fmaf(sq[d + 2], kv.z, s);
            s = fmaf(sq[d + 3], kv.w, s);
        }
        se[kk] = s * scale;
        lmax = fmaxf(lmax, s * scale);
    }
    #pragma unroll
    for (int o2 = 32; o2 > 0; o2 >>= 1) lmax = fmaxf(lmax, __shfl_xor(lmax, o2));
    __syncthreads();
    float lsum = 0.f;
    for (int kk = t; kk < NQ; kk += 64) {
        float e = expf(se[kk] - lmax);
        se[kk] = e;
        lsum += e;
    }
    #pragma unroll
    for (int o2 = 32; o2 > 0; o2 >>= 1) lsum += __shfl_xor(lsum, o2);
    __syncthreads();
    float inv = 1.f / lsum;
    int d = t & 31;
    int half = t >> 5;
    float acc = 0.f;
    for (int kk = half; kk < NQ; kk += 2) {
        acc = fmaf(se[kk], qkv[((size_t)(b * NQ + kk) * (3 * DD)) + 2 * DD + h * HD + d], acc);
    }
    acc += __shfl_xor(acc, 32);
    if (half == 0) attn_o[((size_t)(b * NQ + q)) * DD + h * HD + d] = acc * inv;
}

// ---------------- fused GEMM (4 rows/block) + residual + LayerNorm, in-place on x ---------
template <int K>
__global__ __launch_bounds__(256) void gemm4_res_ln(const float* __restrict__ A,
                                                    const float* __restrict__ Wt,
                                                    const float* __restrict__ bias,
                                                    const float* __restrict__ gam,
                                                    const float* __restrict__ bet,
                                                    float* __restrict__ x) {
    __shared__ float sA[4 * K];
    __shared__ float redS[4][4], redS2[4][4];
    __shared__ float mu[4], ri[4];
    int r0 = blockIdx.x * 4;
    int j = threadIdx.x;
    {
        const float4* Asrc = (const float4*)(A + (size_t)r0 * K);
        float4* sA4 = (float4*)sA;
        for (int i = j; i < K; i += 256) sA4[i] = Asrc[i];
    }
    __syncthreads();
    float acc0 = bias[j], acc1 = acc0, acc2 = acc0, acc3 = acc0;
    const float* wp = Wt + (size_t)j * K;
    for (int k = 0; k < K; k += 4) {
        float4 w  = *(const float4*)(wp + k);
        float4 a0 = *(const float4*)(sA + 0 * K + k);
        float4 a1 = *(const float4*)(sA + 1 * K + k);
        float4 a2 = *(const float4*)(sA + 2 * K + k);
        float4 a3 = *(const float4*)(sA + 3 * K + k);
        acc0 = fmaf(a0.x, w.x, acc0); acc0 = fmaf(a0.y, w.y, acc0); acc0 = fmaf(a0.z, w.z, acc0); acc0 = fmaf(a0.w, w.w, acc0);
        acc1 = fmaf(a1.x, w.x, acc1); acc1 = fmaf(a1.y, w.y, acc1); acc1 = fmaf(a1.z, w.z, acc1); acc1 = fmaf(a1.w, w.w, acc1);
        acc2 = fmaf(a2.x, w.x, acc2); acc2 = fmaf(a2.y, w.y, acc2); acc2 = fmaf(a2.z, w.z, acc2); acc2 = fmaf(a2.w, w.w, acc2);
        acc3 = fmaf(a3.x, w.x, acc3); acc3 = fmaf(a3.y, w.y, acc3); acc3 = fmaf(a3.z, w.z, acc3); acc3 = fmaf(a3.w, w.w, acc3);
    }
    float val[4];
    val[0] = x[(size_t)(r0 + 0) * DD + j] + acc0;
    val[1] = x[(size_t)(r0 + 1) * DD + j] + acc1;
    val[2] = x[(size_t)(r0 + 2) * DD + j] + acc2;
    val[3] = x[(size_t)(r0 + 3) * DD + j] + acc3;
    float s[4], s2[4];
    #pragma unroll
    for (int r = 0; r < 4; ++r) { s[r] = val[r]; s2[r] = val[r] * val[r]; }
    #pragma unroll
    for (int o2 = 32; o2 > 0; o2 >>= 1) {
        #pragma unroll
        for (int r = 0; r < 4; ++r) {
            s[r]  += __shfl_xor(s[r],  o2);
            s2[r] += __shfl_xor(s2[r], o2);
        }
    }
    int wid = j >> 6, lane = j & 63;
    if (lane == 0) {
        #pragma unroll
        for (int r = 0; r < 4; ++r) { redS[r][wid] = s[r]; redS2[r][wid] = s2[r]; }
    }
    __syncthreads();
    if (j < 4) {
        int r = j;
        float ts  = redS[r][0]  + redS[r][1]  + redS[r][2]  + redS[r][3];
        float ts2 = redS2[r][0] + redS2[r][1] + redS2[r][2] + redS2[r][3];
        float mean = ts * (1.f / DD);
        float var = ts2 * (1.f / DD) - mean * mean;
        mu[r] = mean;
        ri[r] = rsqrtf(var + 1e-5f);
    }
    __syncthreads();
    float g = gam[j], be = bet[j];
    #pragma unroll
    for (int r = 0; r < 4; ++r)
        x[(size_t)(r0 + r) * DD + j] = (val[r] - mu[r]) * ri[r] * g + be;
}

// ---------------- FFN first layer: (4 rows) x 1024 cols + ReLU ----------------
__global__ __launch_bounds__(256) void ffn1_kernel(const float* __restrict__ x,
                                                   const float* __restrict__ W1,
                                                   const float* __restrict__ b1,
                                                   float* __restrict__ out) {
    __shared__ float sA[4 * DD];
    int r0 = blockIdx.x * 4;
    int tid = threadIdx.x;
    ((float4*)sA)[tid] = ((const float4*)(x + (size_t)r0 * DD))[tid];
    __syncthreads();
    for (int p = 0; p < 4; ++p) {
        int jj = tid + p * 256;
        float acc0 = b1[jj], acc1 = acc0, acc2 = acc0, acc3 = acc0;
        const float* wp = W1 + (size_t)jj * DD;
        for (int k = 0; k < DD; k += 4) {
            float4 w  = *(const float4*)(wp + k);
            float4 a0 = *(const float4*)(sA + 0 * DD + k);
            float4 a1 = *(const float4*)(sA + 1 * DD + k);
            float4 a2 = *(const float4*)(sA + 2 * DD + k);
            float4 a3 = *(const float4*)(sA + 3 * DD + k);
            acc0 = fmaf(a0.x, w.x, acc0); acc0 = fmaf(a0.y, w.y, acc0); acc0 = fmaf(a0.z, w.z, acc0); acc0 = fmaf(a0.w, w.w, acc0);
            acc1 = fmaf(a1.x, w.x, acc1); acc1 = fmaf(a1.y, w.y, acc1); acc1 = fmaf(a1.z, w.z, acc1); acc1 = fmaf(a1.w, w.w, acc1);
            acc2 = fmaf(a2.x, w.x, acc2); acc2 = fmaf(a2.y, w.y, acc2); acc2 = fmaf(a2.z, w.z, acc2); acc2 = fmaf(a2.w, w.w, acc2);
            acc3 = fmaf(a3.x, w.x, acc3); acc3 = fmaf(a3.y, w.y, acc3); acc3 = fmaf(a3.z, w.z, acc3); acc3 = fmaf(a3.w, w.w, acc3);
        }
        out[(size_t)(r0 + 0) * FF + jj] = fmaxf(acc0, 0.f);
        out[(size_t)(r0 + 1) * FF + jj] = fmaxf(acc1, 0.f);
        out[(size_t)(r0 + 2) * FF + jj] = fmaxf(acc2, 0.f);
        out[(size_t)(r0 + 3) * FF + jj] = fmaxf(acc3, 0.f);
    }
}

// ---------------- bilinear sample one level, one channel ----------------
template <bool TRANSPOSED>
__device__ inline float sample_level(const float* __restrict__ f, int bv, int Hh,
                                     float un, float vn, int dth) {
    int Ww = Hh;
    float xx = (un + 1.f) * Ww * 0.5f - 0.5f;
    float yy = (vn + 1.f) * Hh * 0.5f - 0.5f;
    float x0f = floorf(xx), y0f = floorf(yy);
    int ix0 = (int)x0f, iy0 = (int)y0f;
    float wx1 = xx - x0f, wx0 = 1.f - wx1;
    float wy1 = yy - y0f, wy0 = 1.f - wy1;
    float s = 0.f;
#define TAP(IX, IY, W)                                                           \
    {                                                                            \
        int ix = (IX), iy = (IY);                                                \
        if (ix >= 0 && ix < Ww && iy >= 0 && iy < Hh) {                          \
            float v;                                                             \
            if (TRANSPOSED)                                                      \
                v = f[((size_t)bv * Hh * Ww + (size_t)iy * Ww + ix) * DD + dth]; \
            else                                                                 \
                v = f[(((size_t)bv * DD + dth) * Hh + iy) * Ww + ix];            \
            s = fmaf((W), v, s);                                                 \
        }                                                                        \
    }
    TAP(ix0,     iy0,     wy0 * wx0)
    TAP(ix0 + 1, iy0,     wy0 * wx1)
    TAP(ix0,     iy0 + 1, wy1 * wx0)
    TAP(ix0 + 1, iy0 + 1, wy1 * wx1)
#undef TAP
    return s;
}

// ---------------- fused: project refs (8 views) + multi-level sample + mask fuse ----------
template <bool TRANSPOSED>
__global__ __launch_bounds__(256) void sample_fuse_k(const float* __restrict__ f0,
                                                     const float* __restrict__ f1,
                                                     const float* __restrict__ f2,
                                                     const float* __restrict__ refb,
                                                     const float* __restrict__ Rm,
                                                     const float* __restrict__ Tm,
                                                     const float* __restrict__ Km,
                                                     float* __restrict__ fused) {
    int row = blockIdx.x;            // b*NQ + q
    int dth = threadIdx.x;
    int b = row / NQ;
    __shared__ float sg[VV][4];      // un, vn, mask
    if (dth < VV) {
        int bv = b * VV + dth;
        const float* r = refb + (size_t)row * 3;
        const float* R = Rm + (size_t)bv * 9;
        const float* T = Tm + (size_t)bv * 3;
        const float* K = Km + (size_t)bv * 9;
        float p0 = R[0] * r[0] + R[1] * r[1] + R[2] * r[2] + T[0];
        float p1 = R[3] * r[0] + R[4] * r[1] + R[5] * r[2] + T[1];
        float p2 = R[6] * r[0] + R[7] * r[1] + R[8] * r[2] + T[2];
        float z = fmaxf(p2, 0.1f);
        float u  = p0 * K[0] / z + K[2];
        float vv = p1 * K[4] / z + K[5];
        float un = 2.f * u  / (float)(W_IMG - 1) - 1.f;
        float vn = 2.f * vv / (float)(H_IMG - 1) - 1.f;
        bool m = (un > -1.f) && (un < 1.f) && (vn > -1.f) && (vn < 1.f) && (p2 > 0.f);
        sg[dth][0] = un; sg[dth][1] = vn; sg[dth][2] = m ? 1.f : 0.f;
    }
    __syncthreads();
    float acc = 0.f;
    float cnt = 0.f;
    for (int v = 0; v < VV; ++v) {
        float m = sg[v][2];
        if (m == 0.f) continue;
        int bv = b * VV + v;
        float un = sg[v][0], vn = sg[v][1];
        cnt += 1.f;
        float ms = sample_level<TRANSPOSED>(f0, bv, 64, un, vn, dth)
                 + sample_level<TRANSPOSED>(f1, bv, 32, un, vn, dth)
                 + sample_level<TRANSPOSED>(f2, bv, 16, un, vn, dth);
        acc += ms * (1.f / 3.f);
    }
    fused[(size_t)row * DD + dth] = acc / fmaxf(cnt, 1.f);
}

// ---------------- fused pose MLP (2x256 GEMM+ReLU) + pose delta + cls, 4 rows/block ------
__global__ __launch_bounds__(256) void pose_fused(const float* __restrict__ x,
                                                  const float* __restrict__ W0, const float* __restrict__ b0,
                                                  const float* __restrict__ W1p, const float* __restrict__ b1p,
                                                  const float* __restrict__ W2p, const float* __restrict__ b2p,
                                                  const float* __restrict__ cW, const float* __restrict__ cb,
                                                  float* __restrict__ refb, float* __restrict__ outp) {
    __shared__ float sX[4 * DD];
    __shared__ float sH[4 * DD];
    __shared__ float red[4][4][4];   // [row][out][wave]
    int r0 = blockIdx.x * 4;
    int tid = threadIdx.x;
    ((float4*)sX)[tid] = ((const float4*)(x + (size_t)r0 * DD))[tid];
    __syncthreads();
    // h1 = relu(x @ W0^T + b0)
    {
        float a0 = b0[tid], a1 = a0, a2 = a0, a3 = a0;
        const float* wp = W0 + (size_t)tid * DD;
        for (int k = 0; k < DD; k += 4) {
            float4 w  = *(const float4*)(wp + k);
            float4 x0 = *(const float4*)(sX + 0 * DD + k);
            float4 x1 = *(const float4*)(sX + 1 * DD + k);
            float4 x2 = *(const float4*)(sX + 2 * DD + k);
            float4 x3 = *(const float4*)(sX + 3 * DD + k);
            a0 = fmaf(x0.x, w.x, a0); a0 = fmaf(x0.y, w.y, a0); a0 = fmaf(x0.z, w.z, a0); a0 = fmaf(x0.w, w.w, a0);
            a1 = fmaf(x1.x, w.x, a1); a1 = fmaf(x1.y, w.y, a1); a1 = fmaf(x1.z, w.z, a1); a1 = fmaf(x1.w, w.w, a1);
            a2 = fmaf(x2.x, w.x, a2); a2 = fmaf(x2.y, w.y, a2); a2 = fmaf(x2.z, w.z, a2); a2 = fmaf(x2.w, w.w, a2);
            a3 = fmaf(x3.x, w.x, a3); a3 = fmaf(x3.y, w.y, a3); a3 = fmaf(x3.w, w.w, a3); a3 = fmaf(x3.z, w.z, a3);
        }
        sH[0 * DD + tid] = fmaxf(a0, 0.f);
        sH[1 * DD + tid] = fmaxf(a1, 0.f);
        sH[2 * DD + tid] = fmaxf(a2, 0.f);
        sH[3 * DD + tid] = fmaxf(a3, 0.f);
    }
    __syncthreads();
    // h2 = relu(h1 @ W1^T + b1)
    float h[4];
    {
        float a0 = b1p[tid], a1 = a0, a2 = a0, a3 = a0;
        const float* wp = W1p + (size_t)tid * DD;
        for (int k = 0; k < DD; k += 4) {
            float4 w  = *(const float4*)(wp + k);
            float4 x0 = *(const float4*)(sH + 0 * DD + k);
            float4 x1 = *(const float4*)(sH + 1 * DD + k);
            float4 x2 = *(const float4*)(sH + 2 * DD + k);
            float4 x3 = *(const float4*)(sH + 3 * DD + k);
            a0 = fmaf(x0.x, w.x, a0); a0 = fmaf(x0.y, w.y, a0); a0 = fmaf(x0.z, w.z, a0); a0 = fmaf(x0.w, w.w, a0);
            a1 = fmaf(x1.x, w.x, a1); a1 = fmaf(x1.y, w.y, a1); a1 = fmaf(x1.z, w.z, a1); a1 = fmaf(x1.w, w.w, a1);
            a2 = fmaf(x2.x, w.x, a2); a2 = fmaf(x2.y, w.y, a2); a2 = fmaf(x2.z, w.z, a2); a2 = fmaf(x2.w, w.w, a2);
            a3 = fmaf(x3.x, w.x, a3); a3 = fmaf(x3.y, w.y, a3); a3 = fmaf(x3.z, w.z, a3); a3 = fmaf(x3.w, w.w, a3);
        }
        h[0] = fmaxf(a0, 0.f); h[1] = fmaxf(a1, 0.f); h[2] = fmaxf(a2, 0.f); h[3] = fmaxf(a3, 0.f);
    }
    // 4 dot products per row: pose delta (3) + cls (1)
    float w2a = W2p[tid], w2b = W2p[DD + tid], w2c = W2p[2 * DD + tid], cw = cW[tid];
    float v[4][4];
    #pragma unroll
    for (int r = 0; r < 4; ++r) {
        v[r][0] = h[r] * w2a;
        v[r][1] = h[r] * w2b;
        v[r][2] = h[r] * w2c;
        v[r][3] = sX[r * DD + tid] * cw;
    }
    #pragma unroll
    for (int o2 = 32; o2 > 0; o2 >>= 1) {
        #pragma unroll
        for (int r = 0; r < 4; ++r) {
            #pragma unroll
            for (int c = 0; c < 4; ++c) v[r][c] += __shfl_xor(v[r][c], o2);
        }
    }
    int wid = tid >> 6, lane = tid & 63;
    if (lane == 0) {
        #pragma unroll
        for (int r = 0; r < 4; ++r) {
            #pragma unroll
            for (int c = 0; c < 4; ++c) red[r][c][wid] = v[r][c];
        }
    }
    __syncthreads();
    if (tid < 4) {
        int r = tid;
        float d0 = red[r][0][0] + red[r][0][1] + red[r][0][2] + red[r][0][3] + b2p[0];
        float d1 = red[r][1][0] + red[r][1][1] + red[r][1][2] + red[r][1][3] + b2p[1];
        float d2 = red[r][2][0] + red[r][2][1] + red[r][2][2] + red[r][2][3] + b2p[2];
        float cl = red[r][3][0] + red[r][3][1] + red[r][3][2] + red[r][3][3] + cb[0];
        int row = r0 + r;
        float rx = refb[(size_t)row * 3 + 0] + d0;
        float ry = refb[(size_t)row * 3 + 1] + d1;
        float rz = refb[(size_t)row * 3 + 2] + d2;
        refb[(size_t)row * 3 + 0] = rx;
        refb[(size_t)row * 3 + 1] = ry;
        refb[(size_t)row * 3 + 2] = rz;
        outp[(size_t)row * 4 + 0] = cl;
        outp[(size_t)row * 4 + 1] = rx;
        outp[(size_t)row * 4 + 2] = ry;
        outp[(size_t)row * 4 + 3] = rz;
    }
}

extern "C" void kernel_launch(void* const* d_in, const int* in_sizes, int n_in,
                              void* d_out, int out_size, void* d_ws, size_t ws_size,
                              hipStream_t stream) {
    const float* tgt       = (const float*)d_in[0];
    const float* query_pos = (const float*)d_in[1];
    const float* refpts    = (const float*)d_in[2];
    const float* feat0     = (const float*)d_in[3];
    const float* feat1     = (const float*)d_in[4];
    const float* feat2     = (const float*)d_in[5];
    const float* camR      = (const float*)d_in[6];
    const float* camT      = (const float*)d_in[7];
    const float* camK      = (const float*)d_in[8];
    const float* Wqkv      = (const float*)d_in[9];
    const float* bqkv      = (const float*)d_in[10];
    const float* Wo        = (const float*)d_in[11];
    const float* bo        = (const float*)d_in[12];
    const float* ln1_g     = (const float*)d_in[13];
    const float* ln1_b     = (const float*)d_in[14];
    const float* Wproj     = (const float*)d_in[15];
    const float* bproj     = (const float*)d_in[16];
    const float* pn_g      = (const float*)d_in[17];
    const float* pn_b      = (const float*)d_in[18];
    const float* W1        = (const float*)d_in[19];
    const float* b1        = (const float*)d_in[20];
    const float* W2        = (const float*)d_in[21];
    const float* b2        = (const float*)d_in[22];
    const float* ln2_g     = (const float*)d_in[23];
    const float* ln2_b     = (const float*)d_in[24];
    const float* pose_W0   = (const float*)d_in[25];
    const float* pose_b0   = (const float*)d_in[26];
    const float* pose_W1   = (const float*)d_in[27];
    const float* pose_b1   = (const float*)d_in[28];
    const float* pose_W2   = (const float*)d_in[29];
    const float* pose_b2   = (const float*)d_in[30];
    const float* cls_W     = (const float*)d_in[31];
    const float* cls_b     = (const float*)d_in[32];
    float* out = (float*)d_out;

    float* w = (float*)d_ws;
    size_t off = 0;
    auto alloc = [&](size_t n) { float* p = w + off; off += n; return p; };
    float* x      = alloc((size_t)BQ * DD);
    float* qkv    = alloc((size_t)BQ * 3 * DD);
    float* attn_o = alloc((size_t)BQ * DD);
    float* fused  = alloc((size_t)BQ * DD);
    float* ffh    = alloc((size_t)BQ * FF);
    float* refb   = alloc((size_t)BQ * 3);
    size_t base_floats = off;
    size_t featT_floats = (size_t)BB * VV * DD * (64 * 64 + 32 * 32 + 16 * 16);
    bool useT = ws_size >= (base_floats + featT_floats) * sizeof(float);
    float *fT0 = nullptr, *fT1 = nullptr, *fT2 = nullptr;
    if (useT) {
        fT0 = alloc((size_t)BB * VV * 64 * 64 * DD);
        fT1 = alloc((size_t)BB * VV * 32 * 32 * DD);
        fT2 = alloc((size_t)BB * VV * 16 * 16 * DD);
    }

    hipMemcpyAsync(x, tgt, (size_t)BQ * DD * sizeof(float), hipMemcpyDeviceToDevice, stream);
    hipMemcpyAsync(refb, refpts, (size_t)BQ * 3 * sizeof(float), hipMemcpyDeviceToDevice, stream);

    if (useT)
        transpose_all<<<5376, 256, 0, stream>>>(feat0, feat1, feat2, fT0, fT1, fT2);

    for (int l = 0; l < NL; ++l) {
        qkv4_kernel<<<BQ / 4, 256, 0, stream>>>(x, query_pos,
                                                Wqkv + (size_t)l * 3 * DD * DD,
                                                bqkv + (size_t)l * 3 * DD, qkv);
        attn_kernel<<<BB * HEADS * NQ, 64, 0, stream>>>(qkv, attn_o);
        gemm4_res_ln<DD><<<BQ / 4, 256, 0, stream>>>(attn_o,
                                                     Wo + (size_t)l * DD * DD, bo + (size_t)l * DD,
                                                     ln1_g + (size_t)l * DD, ln1_b + (size_t)l * DD, x);
        if (useT)
            sample_fuse_k<true><<<BQ, 256, 0, stream>>>(fT0, fT1, fT2, refb, camR, camT, camK, fused);
        else
            sample_fuse_k<false><<<BQ, 256, 0, stream>>>(feat0, feat1, feat2, refb, camR, camT, camK, fused);
        gemm4_res_ln<DD><<<BQ / 4, 256, 0, stream>>>(fused,
                                                     Wproj + (size_t)l * DD * DD, bproj + (size_t)l * DD,
                                                     pn_g + (size_t)l * DD, pn_b + (size_t)l * DD, x);
        ffn1_kernel<<<BQ / 4, 256, 0, stream>>>(x, W1 + (size_t)l * FF * DD,
                                                b1 + (size_t)l * FF, ffh);
        gemm4_res_ln<FF><<<BQ / 4, 256, 0, stream>>>(ffh,
                                                     W2 + (size_t)l * DD * FF, b2 + (size_t)l * DD,
                                                     ln2_g + (size_t)l * DD, ln2_b + (size_t)l * DD, x);
        pose_fused<<<BQ / 4, 256, 0, stream>>>(x, pose_W0, pose_b0, pose_W1, pose_b1,
                                               pose_W2, pose_b2, cls_W, cls_b,
                                               refb, out + (size_t)l * BQ * 4);
    }
}

// Round 3
// 1254.294 us; speedup vs baseline: 2.3993x; 1.5501x over previous
//
#include <hip/hip_runtime.h>
#include <math.h>

#define BB 2
#define VV 8
#define NQ 336
#define DD 256
#define HEADS 8
#define HD 32
#define FF 1024
#define NL 6
#define BQ (BB*NQ)
#define W_IMG 512
#define H_IMG 512
#define SP 384                    // padded seq stride for S / score tiles
#define MROWS (BQ)                // 672 = 21*32

// ---------------- merged LDS-tiled transpose: (BV,D,H,W) -> (BV,H,W,D) for all 3 levels ----
__global__ __launch_bounds__(256) void transpose_all(const float* __restrict__ f0,
                                                     const float* __restrict__ f1,
                                                     const float* __restrict__ f2,
                                                     float* __restrict__ o0,
                                                     float* __restrict__ o1,
                                                     float* __restrict__ o2) {
    int b = blockIdx.x;
    const float* src; float* dst; int HW, ptiles;
    if (b < 4096)      { src = f0; dst = o0; HW = 4096; ptiles = 64; }
    else if (b < 5120) { b -= 4096; src = f1; dst = o1; HW = 1024; ptiles = 16; }
    else               { b -= 5120; src = f2; dst = o2; HW = 256;  ptiles = 4;  }
    int cg = b & 3;
    int pt = (b >> 2) % ptiles;
    int bv = (b >> 2) / ptiles;
    int d0 = cg * 64, p0 = pt * 64;
    __shared__ float tile[64][65];
    int tid = threadIdx.x;
    int t4 = tid >> 4, t15 = tid & 15;
    #pragma unroll
    for (int pass = 0; pass < 4; ++pass) {
        int d = pass * 16 + t4;
        int p = t15 * 4;
        float4 v = *(const float4*)(src + ((size_t)(bv * DD + d0 + d)) * HW + p0 + p);
        tile[d][p] = v.x; tile[d][p + 1] = v.y; tile[d][p + 2] = v.z; tile[d][p + 3] = v.w;
    }
    __syncthreads();
    #pragma unroll
    for (int pass = 0; pass < 4; ++pass) {
        int p = pass * 16 + t4;
        int d = t15 * 4;
        float4 v = make_float4(tile[d][p], tile[d + 1][p], tile[d + 2][p], tile[d + 3][p]);
        *(float4*)(dst + ((size_t)bv * HW + p0 + p) * DD + d0 + d) = v;
    }
}

// ---------------- init: x = 0, xq = query_pos ----------------
__global__ __launch_bounds__(256) void init_x(const float* __restrict__ qp,
                                              float* __restrict__ x,
                                              float* __restrict__ xq) {
    int i = blockIdx.x * 256 + threadIdx.x;
    float4 q = ((const float4*)qp)[i];
    ((float4*)x)[i] = make_float4(0.f, 0.f, 0.f, 0.f);
    ((float4*)xq)[i] = q;
}

// ---------------- tiled GEMM: C[M=672, N] = A[M,K] @ W[N,K]^T (+bias) ----------------
// tile 32x64, 256 threads, 2x4 micro. MODE 0: plain, 1: relu, 2: qkv head-packed layout.
// grid: (21, N/64, KSPLIT). Kper = Ktot/KSPLIT. Partial k-split outputs at O0 + kz*672*Nout.
template <int MODE>
__global__ __launch_bounds__(256) void gemm_tile(const float* __restrict__ Aq,
                                                 const float* __restrict__ Ax,
                                                 const float* __restrict__ W,
                                                 const float* __restrict__ bias,
                                                 float* __restrict__ O0,
                                                 float* __restrict__ O1,
                                                 float* __restrict__ O2,
                                                 int Ktot, int Kper, int Nout) {
    __shared__ float At[32][34];
    __shared__ float Wt[32][68];
    int t = threadIdx.x;
    int m0 = blockIdx.x * 32;
    int n0 = blockIdx.y * 64;
    int kz = blockIdx.z;
    int kofs = kz * Kper;
    const float* A = (MODE == 2 && blockIdx.y < 8) ? Aq : Ax;
    int tx = t & 15, ty = t >> 4;
    int nc = n0 + tx * 4;
    float acc0[4], acc1[4];
    {
        float4 bv = make_float4(0.f, 0.f, 0.f, 0.f);
        if (bias && kz == 0) bv = *(const float4*)(bias + nc);
        acc0[0] = bv.x; acc0[1] = bv.y; acc0[2] = bv.z; acc0[3] = bv.w;
        acc1[0] = bv.x; acc1[1] = bv.y; acc1[2] = bv.z; acc1[3] = bv.w;
    }
    int am = t >> 3, ak4 = (t & 7) * 4;
    int ktiles = Kper >> 5;
    for (int kt = 0; kt < ktiles; ++kt) {
        int kk = kofs + kt * 32;
        __syncthreads();
        {
            float4 v = *(const float4*)(A + (size_t)(m0 + am) * Ktot + kk + ak4);
            At[ak4 + 0][am] = v.x; At[ak4 + 1][am] = v.y;
            At[ak4 + 2][am] = v.z; At[ak4 + 3][am] = v.w;
        }
        #pragma unroll
        for (int s = 0; s < 2; ++s) {
            int idx = t + s * 256;
            int wn = idx >> 3, wk4 = (idx & 7) * 4;
            float4 v = *(const float4*)(W + (size_t)(n0 + wn) * Ktot + kk + wk4);
            Wt[wk4 + 0][wn] = v.x; Wt[wk4 + 1][wn] = v.y;
            Wt[wk4 + 2][wn] = v.z; Wt[wk4 + 3][wn] = v.w;
        }
        __syncthreads();
        #pragma unroll
        for (int k = 0; k < 32; ++k) {
            float2 av = *(const float2*)&At[k][ty * 2];
            float4 wv = *(const float4*)&Wt[k][tx * 4];
            acc0[0] = fmaf(av.x, wv.x, acc0[0]); acc0[1] = fmaf(av.x, wv.y, acc0[1]);
            acc0[2] = fmaf(av.x, wv.z, acc0[2]); acc0[3] = fmaf(av.x, wv.w, acc0[3]);
            acc1[0] = fmaf(av.y, wv.x, acc1[0]); acc1[1] = fmaf(av.y, wv.y, acc1[1]);
            acc1[2] = fmaf(av.y, wv.z, acc1[2]); acc1[3] = fmaf(av.y, wv.w, acc1[3]);
        }
    }
    int mr = m0 + ty * 2;
    if (MODE == 2) {
        int kind = nc >> 8;
        float* base = kind == 0 ? O0 : (kind == 1 ? O1 : O2);
        int h = (nc >> 5) & 7, d4 = nc & 31;
        #pragma unroll
        for (int i = 0; i < 2; ++i) {
            int m = mr + i;
            int b = m / NQ, q = m - b * NQ;
            float* p = base + ((size_t)((b << 3) + h) * NQ + q) * HD + d4;
            float* src = i == 0 ? acc0 : acc1;
            *(float4*)p = make_float4(src[0], src[1], src[2], src[3]);
        }
    } else {
        if (MODE == 1) {
            #pragma unroll
            for (int j = 0; j < 4; ++j) { acc0[j] = fmaxf(acc0[j], 0.f); acc1[j] = fmaxf(acc1[j], 0.f); }
        }
        float* Cb = O0 + (size_t)kz * MROWS * Nout;
        *(float4*)(Cb + (size_t)mr * Nout + nc)       = make_float4(acc0[0], acc0[1], acc0[2], acc0[3]);
        *(float4*)(Cb + (size_t)(mr + 1) * Nout + nc) = make_float4(acc1[0], acc1[1], acc1[2], acc1[3]);
    }
}

// ---------------- attention scores: S[bh][q][k] = scale * Qp[bh][q]·Kp[bh][k] ----------------
// grid (16 bh, 6 qtiles of 64). S has padded stride SP=384 both dims; pad entries = 0.
__global__ __launch_bounds__(256) void attn_scores(const float* __restrict__ Qp,
                                                   const float* __restrict__ Kp,
                                                   float* __restrict__ S) {
    int bh = blockIdx.x, qt = blockIdx.y;
    __shared__ float QT[32][68];
    __shared__ float KT[32][68];
    int t = threadIdx.x;
    const float scale = 0.17677669529663687f;
    const float* Qb = Qp + (size_t)bh * NQ * HD;
    const float* Kb = Kp + (size_t)bh * NQ * HD;
    #pragma unroll
    for (int s = 0; s < 2; ++s) {
        int idx = t + s * 256;
        int ql = idx >> 3, d4 = (idx & 7) * 4;
        int qg = qt * 64 + ql;
        float4 v = (qg < NQ) ? *(const float4*)(Qb + (size_t)qg * HD + d4)
                             : make_float4(0.f, 0.f, 0.f, 0.f);
        QT[d4 + 0][ql] = v.x * scale; QT[d4 + 1][ql] = v.y * scale;
        QT[d4 + 2][ql] = v.z * scale; QT[d4 + 3][ql] = v.w * scale;
    }
    int tx = t & 15, ty = t >> 4;
    for (int kt = 0; kt < 6; ++kt) {
        __syncthreads();
        #pragma unroll
        for (int s = 0; s < 2; ++s) {
            int idx = t + s * 256;
            int kl = idx >> 3, d4 = (idx & 7) * 4;
            int kg = kt * 64 + kl;
            float4 v = (kg < NQ) ? *(const float4*)(Kb + (size_t)kg * HD + d4)
                                 : make_float4(0.f, 0.f, 0.f, 0.f);
            KT[d4 + 0][kl] = v.x; KT[d4 + 1][kl] = v.y;
            KT[d4 + 2][kl] = v.z; KT[d4 + 3][kl] = v.w;
        }
        __syncthreads();
        float a0[4] = {0, 0, 0, 0}, a1[4] = {0, 0, 0, 0}, a2[4] = {0, 0, 0, 0}, a3[4] = {0, 0, 0, 0};
        #pragma unroll
        for (int k = 0; k < 32; ++k) {
            float4 qv = *(const float4*)&QT[k][ty * 4];
            float4 kv = *(const float4*)&KT[k][tx * 4];
            a0[0] = fmaf(qv.x, kv.x, a0[0]); a0[1] = fmaf(qv.x, kv.y, a0[1]);
            a0[2] = fmaf(qv.x, kv.z, a0[2]); a0[3] = fmaf(qv.x, kv.w, a0[3]);
            a1[0] = fmaf(qv.y, kv.x, a1[0]); a1[1] = fmaf(qv.y, kv.y, a1[1]);
            a1[2] = fmaf(qv.y, kv.z, a1[2]); a1[3] = fmaf(qv.y, kv.w, a1[3]);
            a2[0] = fmaf(qv.z, kv.x, a2[0]); a2[1] = fmaf(qv.z, kv.y, a2[1]);
            a2[2] = fmaf(qv.z, kv.z, a2[2]); a2[3] = fmaf(qv.z, kv.w, a2[3]);
            a3[0] = fmaf(qv.w, kv.x, a3[0]); a3[1] = fmaf(qv.w, kv.y, a3[1]);
            a3[2] = fmaf(qv.w, kv.z, a3[2]); a3[3] = fmaf(qv.w, kv.w, a3[3]);
        }
        int qg0 = qt * 64 + ty * 4;
        int kg0 = kt * 64 + tx * 4;
        float* Sb = S + ((size_t)bh * SP + qg0) * SP + kg0;
        *(float4*)(Sb + 0 * SP) = make_float4(a0[0], a0[1], a0[2], a0[3]);
        *(float4*)(Sb + 1 * SP) = make_float4(a1[0], a1[1], a1[2], a1[3]);
        *(float4*)(Sb + 2 * SP) = make_float4(a2[0], a2[1], a2[2], a2[3]);
        *(float4*)(Sb + 3 * SP) = make_float4(a3[0], a3[1], a3[2], a3[3]);
    }
}

// ---------------- softmax over valid 336 cols, one wave per row ----------------
__global__ __launch_bounds__(256) void attn_softmax(float* __restrict__ S) {
    int r = blockIdx.x * 4 + (threadIdx.x >> 6);
    int lane = threadIdx.x & 63;
    int bh = r / NQ;
    int q = r - bh * NQ;
    float* row = S + ((size_t)bh * SP + q) * SP;
    float v[6];
    float m = -1e30f;
    #pragma unroll
    for (int i = 0; i < 6; ++i) {
        int k = lane + i * 64;
        v[i] = (k < NQ) ? row[k] : -1e30f;
        m = fmaxf(m, v[i]);
    }
    #pragma unroll
    for (int o = 32; o > 0; o >>= 1) m = fmaxf(m, __shfl_xor(m, o));
    float s = 0.f;
    #pragma unroll
    for (int i = 0; i < 6; ++i) {
        int k = lane + i * 64;
        v[i] = (k < NQ) ? expf(v[i] - m) : 0.f;
        s += v[i];
    }
    #pragma unroll
    for (int o = 32; o > 0; o >>= 1) s += __shfl_xor(s, o);
    float inv = 1.f / s;
    #pragma unroll
    for (int i = 0; i < 6; ++i) {
        int k = lane + i * 64;
        if (k < NQ) row[k] = v[i] * inv;
    }
}

// ---------------- PV: O[b][q][h*32+d] = sum_k P[bh][q][k] * V[bh][k][d] ----------------
// grid (16 bh, 6 qtiles of 64). 256 threads: tx=8 (d0=tx*4), ty=32 (q0=ty*2).
__global__ __launch_bounds__(256) void attn_pv(const float* __restrict__ S,
                                               const float* __restrict__ Vp,
                                               float* __restrict__ O) {
    int bh = blockIdx.x, qt = blockIdx.y;
    int b = bh >> 3, h = bh & 7;
    __shared__ float Pt[64][65];
    __shared__ float Vt[64][32];
    int t = threadIdx.x;
    int tx = t & 7, ty = t >> 3;
    int d0 = tx * 4, q0 = ty * 2;
    float acc0[4] = {0, 0, 0, 0}, acc1[4] = {0, 0, 0, 0};
    for (int kt = 0; kt < 6; ++kt) {
        __syncthreads();
        #pragma unroll
        for (int s = 0; s < 4; ++s) {
            int idx = t + s * 256;
            int ql = idx >> 4, kk4 = (idx & 15) * 4;
            float4 v = *(const float4*)(S + ((size_t)bh * SP + qt * 64 + ql) * SP + kt * 64 + kk4);
            Pt[ql][kk4 + 0] = v.x; Pt[ql][kk4 + 1] = v.y;
            Pt[ql][kk4 + 2] = v.z; Pt[ql][kk4 + 3] = v.w;
        }
        #pragma unroll
        for (int s = 0; s < 2; ++s) {
            int idx = t + s * 256;
            int kl = idx >> 3, d4 = (idx & 7) * 4;
            int kg = kt * 64 + kl;
            float4 v = (kg < NQ) ? *(const float4*)(Vp + ((size_t)bh * NQ + kg) * HD + d4)
                                 : make_float4(0.f, 0.f, 0.f, 0.f);
            *(float4*)&Vt[kl][d4] = v;
        }
        __syncthreads();
        #pragma unroll 8
        for (int kk = 0; kk < 64; ++kk) {
            float4 vv = *(const float4*)&Vt[kk][d0];
            float p0 = Pt[q0][kk], p1 = Pt[q0 + 1][kk];
            acc0[0] = fmaf(p0, vv.x, acc0[0]); acc0[1] = fmaf(p0, vv.y, acc0[1]);
            acc0[2] = fmaf(p0, vv.z, acc0[2]); acc0[3] = fmaf(p0, vv.w, acc0[3]);
            acc1[0] = fmaf(p1, vv.x, acc1[0]); acc1[1] = fmaf(p1, vv.y, acc1[1]);
            acc1[2] = fmaf(p1, vv.z, acc1[2]); acc1[3] = fmaf(p1, vv.w, acc1[3]);
        }
    }
    int qg = qt * 64 + q0;
    if (qg < NQ)
        *(float4*)(O + ((size_t)(b * NQ + qg)) * DD + h * HD + d0) =
            make_float4(acc0[0], acc0[1], acc0[2], acc0[3]);
    if (qg + 1 < NQ)
        *(float4*)(O + ((size_t)(b * NQ + qg + 1)) * DD + h * HD + d0) =
            make_float4(acc1[0], acc1[1], acc1[2], acc1[3]);
}

// ---------------- residual + LayerNorm over NP k-split partials; optional xq = out + qp ----
template <int NP>
__global__ __launch_bounds__(256) void ln_res(float* __restrict__ x,
                                              const float* __restrict__ C,
                                              const float* __restrict__ gam,
                                              const float* __restrict__ bet,
                                              const float* __restrict__ qp,
                                              float* __restrict__ xq) {
    __shared__ float redS[4][4], redS2[4][4];
    __shared__ float mu[4], ri[4];
    int r0 = blockIdx.x * 4;
    int j = threadIdx.x;
    float val[4];
    #pragma unroll
    for (int r = 0; r < 4; ++r) {
        float a = x[(size_t)(r0 + r) * DD + j];
        #pragma unroll
        for (int p = 0; p < NP; ++p) a += C[(size_t)p * MROWS * DD + (size_t)(r0 + r) * DD + j];
        val[r] = a;
    }
    float s[4], s2[4];
    #pragma unroll
    for (int r = 0; r < 4; ++r) { s[r] = val[r]; s2[r] = val[r] * val[r]; }
    #pragma unroll
    for (int o = 32; o > 0; o >>= 1) {
        #pragma unroll
        for (int r = 0; r < 4; ++r) {
            s[r]  += __shfl_xor(s[r],  o);
            s2[r] += __shfl_xor(s2[r], o);
        }
    }
    int wid = j >> 6, lane = j & 63;
    if (lane == 0) {
        #pragma unroll
        for (int r = 0; r < 4; ++r) { redS[r][wid] = s[r]; redS2[r][wid] = s2[r]; }
    }
    __syncthreads();
    if (j < 4) {
        int r = j;
        float ts  = redS[r][0]  + redS[r][1]  + redS[r][2]  + redS[r][3];
        float ts2 = redS2[r][0] + redS2[r][1] + redS2[r][2] + redS2[r][3];
        float mean = ts * (1.f / DD);
        float var = ts2 * (1.f / DD) - mean * mean;
        mu[r] = mean;
        ri[r] = rsqrtf(var + 1e-5f);
    }
    __syncthreads();
    float g = gam[j], be = bet[j];
    #pragma unroll
    for (int r = 0; r < 4; ++r) {
        float o = (val[r] - mu[r]) * ri[r] * g + be;
        x[(size_t)(r0 + r) * DD + j] = o;
        if (qp) xq[(size_t)(r0 + r) * DD + j] = o + qp[(size_t)(r0 + r) * DD + j];
    }
}

// ---------------- bilinear sample one level, one channel ----------------
template <bool TRANSPOSED>
__device__ inline float sample_level(const float* __restrict__ f, int bv, int Hh,
                                     float un, float vn, int dth) {
    int Ww = Hh;
    float xx = (un + 1.f) * Ww * 0.5f - 0.5f;
    float yy = (vn + 1.f) * Hh * 0.5f - 0.5f;
    float x0f = floorf(xx), y0f = floorf(yy);
    int ix0 = (int)x0f, iy0 = (int)y0f;
    float wx1 = xx - x0f, wx0 = 1.f - wx1;
    float wy1 = yy - y0f, wy0 = 1.f - wy1;
    float s = 0.f;
#define TAP(IX, IY, W)                                                           \
    {                                                                            \
        int ix = (IX), iy = (IY);                                                \
        if (ix >= 0 && ix < Ww && iy >= 0 && iy < Hh) {                          \
            float v;                                                             \
            if (TRANSPOSED)                                                      \
                v = f[((size_t)bv * Hh * Ww + (size_t)iy * Ww + ix) * DD + dth]; \
            else                                                                 \
                v = f[(((size_t)bv * DD + dth) * Hh + iy) * Ww + ix];            \
            s = fmaf((W), v, s);                                                 \
        }                                                                        \
    }
    TAP(ix0,     iy0,     wy0 * wx0)
    TAP(ix0 + 1, iy0,     wy0 * wx1)
    TAP(ix0,     iy0 + 1, wy1 * wx0)
    TAP(ix0 + 1, iy0 + 1, wy1 * wx1)
#undef TAP
    return s;
}

// ---------------- fused: project refs (8 views) + multi-level sample + mask fuse ----------
template <bool TRANSPOSED>
__global__ __launch_bounds__(256) void sample_fuse_k(const float* __restrict__ f0,
                                                     const float* __restrict__ f1,
                                                     const float* __restrict__ f2,
                                                     const float* __restrict__ refb,
                                                     const float* __restrict__ Rm,
                                                     const float* __restrict__ Tm,
                                                     const float* __restrict__ Km,
                                                     float* __restrict__ fused) {
    int row = blockIdx.x;            // b*NQ + q
    int dth = threadIdx.x;
    int b = row / NQ;
    __shared__ float sg[VV][4];      // un, vn, mask
    if (dth < VV) {
        int bv = b * VV + dth;
        const float* r = refb + (size_t)row * 3;
        const float* R = Rm + (size_t)bv * 9;
        const float* T = Tm + (size_t)bv * 3;
        const float* K = Km + (size_t)bv * 9;
        float p0 = R[0] * r[0] + R[1] * r[1] + R[2] * r[2] + T[0];
        float p1 = R[3] * r[0] + R[4] * r[1] + R[5] * r[2] + T[1];
        float p2 = R[6] * r[0] + R[7] * r[1] + R[8] * r[2] + T[2];
        float z = fmaxf(p2, 0.1f);
        float u  = p0 * K[0] / z + K[2];
        float vv = p1 * K[4] / z + K[5];
        float un = 2.f * u  / (float)(W_IMG - 1) - 1.f;
        float vn = 2.f * vv / (float)(H_IMG - 1) - 1.f;
        bool m = (un > -1.f) && (un < 1.f) && (vn > -1.f) && (vn < 1.f) && (p2 > 0.f);
        sg[dth][0] = un; sg[dth][1] = vn; sg[dth][2] = m ? 1.f : 0.f;
    }
    __syncthreads();
    float acc = 0.f;
    float cnt = 0.f;
    for (int v = 0; v < VV; ++v) {
        float m = sg[v][2];
        if (m == 0.f) continue;
        int bv = b * VV + v;
        float un = sg[v][0], vn = sg[v][1];
        cnt += 1.f;
        float ms = sample_level<TRANSPOSED>(f0, bv, 64, un, vn, dth)
                 + sample_level<TRANSPOSED>(f1, bv, 32, un, vn, dth)
                 + sample_level<TRANSPOSED>(f2, bv, 16, un, vn, dth);
        acc += ms * (1.f / 3.f);
    }
    fused[(size_t)row * DD + dth] = acc / fmaxf(cnt, 1.f);
}

// ---------------- pose delta (3 dots from h2) + classification (1 dot from x) ------------
__global__ __launch_bounds__(256) void pose_cls(const float* __restrict__ h2,
                                                const float* __restrict__ x,
                                                const float* __restrict__ pw2,
                                                const float* __restrict__ pb2,
                                                const float* __restrict__ cW,
                                                const float* __restrict__ cb,
                                                float* __restrict__ refb,
                                                float* __restrict__ outp) {
    int row = blockIdx.x;
    int tid = threadIdx.x;
    __shared__ float rbuf[4][4];
    float hv = h2[(size_t)row * DD + tid];
    float xv = x[(size_t)row * DD + tid];
    float v0 = hv * pw2[tid];
    float v1 = hv * pw2[DD + tid];
    float v2 = hv * pw2[2 * DD + tid];
    float v3 = xv * cW[tid];
    #pragma unroll
    for (int o2 = 32; o2 > 0; o2 >>= 1) {
        v0 += __shfl_down(v0, o2);
        v1 += __shfl_down(v1, o2);
        v2 += __shfl_down(v2, o2);
        v3 += __shfl_down(v3, o2);
    }
    int wid = tid >> 6, lane = tid & 63;
    if (lane == 0) { rbuf[0][wid] = v0; rbuf[1][wid] = v1; rbuf[2][wid] = v2; rbuf[3][wid] = v3; }
    __syncthreads();
    if (tid == 0) {
        float d0 = rbuf[0][0] + rbuf[0][1] + rbuf[0][2] + rbuf[0][3] + pb2[0];
        float d1 = rbuf[1][0] + rbuf[1][1] + rbuf[1][2] + rbuf[1][3] + pb2[1];
        float d2 = rbuf[2][0] + rbuf[2][1] + rbuf[2][2] + rbuf[2][3] + pb2[2];
        float cl = rbuf[3][0] + rbuf[3][1] + rbuf[3][2] + rbuf[3][3] + cb[0];
        float r0 = refb[(size_t)row * 3 + 0] + d0;
        float r1 = refb[(size_t)row * 3 + 1] + d1;
        float r2 = refb[(size_t)row * 3 + 2] + d2;
        refb[(size_t)row * 3 + 0] = r0;
        refb[(size_t)row * 3 + 1] = r1;
        refb[(size_t)row * 3 + 2] = r2;
        outp[(size_t)row * 4 + 0] = cl;
        outp[(size_t)row * 4 + 1] = r0;
        outp[(size_t)row * 4 + 2] = r1;
        outp[(size_t)row * 4 + 3] = r2;
    }
}

extern "C" void kernel_launch(void* const* d_in, const int* in_sizes, int n_in,
                              void* d_out, int out_size, void* d_ws, size_t ws_size,
                              hipStream_t stream) {
    const float* tgt       = (const float*)d_in[0];
    const float* query_pos = (const float*)d_in[1];
    const float* refpts    = (const float*)d_in[2];
    const float* feat0     = (const float*)d_in[3];
    const float* feat1     = (const float*)d_in[4];
    const float* feat2     = (const float*)d_in[5];
    const float* camR      = (const float*)d_in[6];
    const float* camT      = (const float*)d_in[7];
    const float* camK      = (const float*)d_in[8];
    const float* Wqkv      = (const float*)d_in[9];
    const float* bqkv      = (const float*)d_in[10];
    const float* Wo        = (const float*)d_in[11];
    const float* bo        = (const float*)d_in[12];
    const float* ln1_g     = (const float*)d_in[13];
    const float* ln1_b     = (const float*)d_in[14];
    const float* Wproj     = (const float*)d_in[15];
    const float* bproj     = (const float*)d_in[16];
    const float* pn_g      = (const float*)d_in[17];
    const float* pn_b      = (const float*)d_in[18];
    const float* W1        = (const float*)d_in[19];
    const float* b1        = (const float*)d_in[20];
    const float* W2        = (const float*)d_in[21];
    const float* b2        = (const float*)d_in[22];
    const float* ln2_g     = (const float*)d_in[23];
    const float* ln2_b     = (const float*)d_in[24];
    const float* pose_W0   = (const float*)d_in[25];
    const float* pose_b0   = (const float*)d_in[26];
    const float* pose_W1   = (const float*)d_in[27];
    const float* pose_b1   = (const float*)d_in[28];
    const float* pose_W2   = (const float*)d_in[29];
    const float* pose_b2   = (const float*)d_in[30];
    const float* cls_W     = (const float*)d_in[31];
    const float* cls_b     = (const float*)d_in[32];
    float* out = (float*)d_out;

    float* w = (float*)d_ws;
    size_t off = 0;
    auto alloc = [&](size_t n) { float* p = w + off; off += n; return p; };
    float* x      = alloc((size_t)BQ * DD);
    float* xq     = alloc((size_t)BQ * DD);
    float* Qp     = alloc((size_t)BB * HEADS * NQ * HD);
    float* Kp     = alloc((size_t)BB * HEADS * NQ * HD);
    float* Vp     = alloc((size_t)BB * HEADS * NQ * HD);
    float* S      = alloc((size_t)BB * HEADS * SP * SP);
    float* attn_o = alloc((size_t)BQ * DD);
    float* fused  = alloc((size_t)BQ * DD);
    float* ffh    = alloc((size_t)BQ * FF);
    float* ctmp   = alloc((size_t)4 * BQ * DD);
    float* h1b    = alloc((size_t)BQ * DD);
    float* h2b    = alloc((size_t)BQ * DD);
    float* refb   = alloc((size_t)BQ * 3 + 64);
    size_t base_floats = off;
    size_t featT_floats = (size_t)BB * VV * DD * (64 * 64 + 32 * 32 + 16 * 16);
    bool useT = ws_size >= (base_floats + featT_floats) * sizeof(float);
    float *fT0 = nullptr, *fT1 = nullptr, *fT2 = nullptr;
    if (useT) {
        fT0 = alloc((size_t)BB * VV * 64 * 64 * DD);
        fT1 = alloc((size_t)BB * VV * 32 * 32 * DD);
        fT2 = alloc((size_t)BB * VV * 16 * 16 * DD);
    }

    hipMemcpyAsync(refb, refpts, (size_t)BQ * 3 * sizeof(float), hipMemcpyDeviceToDevice, stream);
    init_x<<<BQ * DD / 4 / 256, 256, 0, stream>>>(query_pos, x, xq);
    if (useT)
        transpose_all<<<5376, 256, 0, stream>>>(feat0, feat1, feat2, fT0, fT1, fT2);

    for (int l = 0; l < NL; ++l) {
        // QKV projection: q,k from xq, v from x; head-packed outputs
        gemm_tile<2><<<dim3(21, 12, 1), 256, 0, stream>>>(
            xq, x, Wqkv + (size_t)l * 3 * DD * DD, bqkv + (size_t)l * 3 * DD,
            Qp, Kp, Vp, DD, DD, 0);
        attn_scores<<<dim3(BB * HEADS, 6), 256, 0, stream>>>(Qp, Kp, S);
        attn_softmax<<<BB * HEADS * NQ / 4, 256, 0, stream>>>(S);
        attn_pv<<<dim3(BB * HEADS, 6), 256, 0, stream>>>(S, Vp, attn_o);
        // O-projection + residual + LN1
        gemm_tile<0><<<dim3(21, 4, 1), 256, 0, stream>>>(
            attn_o, attn_o, Wo + (size_t)l * DD * DD, bo + (size_t)l * DD,
            ctmp, nullptr, nullptr, DD, DD, DD);
        ln_res<1><<<BQ / 4, 256, 0, stream>>>(x, ctmp, ln1_g + (size_t)l * DD,
                                              ln1_b + (size_t)l * DD, nullptr, nullptr);
        // projective attention
        if (useT)
            sample_fuse_k<true><<<BQ, 256, 0, stream>>>(fT0, fT1, fT2, refb, camR, camT, camK, fused);
        else
            sample_fuse_k<false><<<BQ, 256, 0, stream>>>(feat0, feat1, feat2, refb, camR, camT, camK, fused);
        gemm_tile<0><<<dim3(21, 4, 1), 256, 0, stream>>>(
            fused, fused, Wproj + (size_t)l * DD * DD, bproj + (size_t)l * DD,
            ctmp, nullptr, nullptr, DD, DD, DD);
        ln_res<1><<<BQ / 4, 256, 0, stream>>>(x, ctmp, pn_g + (size_t)l * DD,
                                              pn_b + (size_t)l * DD, nullptr, nullptr);
        // FFN
        gemm_tile<1><<<dim3(21, 16, 1), 256, 0, stream>>>(
            x, x, W1 + (size_t)l * FF * DD, b1 + (size_t)l * FF,
            ffh, nullptr, nullptr, DD, DD, FF);
        gemm_tile<0><<<dim3(21, 4, 4), 256, 0, stream>>>(
            ffh, ffh, W2 + (size_t)l * DD * FF, b2 + (size_t)l * DD,
            ctmp, nullptr, nullptr, FF, FF / 4, DD);
        ln_res<4><<<BQ / 4, 256, 0, stream>>>(x, ctmp, ln2_g + (size_t)l * DD,
                                              ln2_b + (size_t)l * DD, query_pos, xq);
        // pose MLP + heads
        gemm_tile<1><<<dim3(21, 4, 1), 256, 0, stream>>>(
            x, x, pose_W0, pose_b0, h1b, nullptr, nullptr, DD, DD, DD);
        gemm_tile<1><<<dim3(21, 4, 1), 256, 0, stream>>>(
            h1b, h1b, pose_W1, pose_b1, h2b, nullptr, nullptr, DD, DD, DD);
        pose_cls<<<BQ, 256, 0, stream>>>(h2b, x, pose_W2, pose_b2, cls_W, cls_b,
                                         refb, out + (size_t)l * BQ * 4);
    }
}